// Round 11
// baseline (830.441 us; speedup 1.0000x reference)
//
#include <hip/hip_runtime.h>
#include <stdint.h>

#define HW 4096

typedef unsigned short u16;
typedef unsigned int u32;
typedef __attribute__((ext_vector_type(8))) short bf16x8;
typedef __attribute__((ext_vector_type(4))) float f32x4;
typedef __attribute__((address_space(1))) const unsigned int g_u32;
typedef __attribute__((address_space(3))) unsigned int l_u32;

__device__ __forceinline__ u16 f2bf(float f) {
  union { float f; unsigned u; } v; v.f = f;
  unsigned r = v.u + 0x7FFFu + ((v.u >> 16) & 1u);
  return (u16)(r >> 16);
}

__device__ __forceinline__ void gld16(const void* gsrc, void* ldst) {
  __builtin_amdgcn_global_load_lds((g_u32*)(uintptr_t)gsrc, (l_u32*)(uintptr_t)ldst, 16, 0, 0);
}

// ---------- K0: W fp32 -> bf16 (row-major [o][c]) ----------
__global__ void k_wb(const float* __restrict__ W, u16* __restrict__ wb) {
  int g = blockIdx.x * 256 + threadIdx.x;
  float4 v = ((const float4*)W)[g];
  ushort4 o;
  o.x = f2bf(v.x); o.y = f2bf(v.y); o.z = f2bf(v.z); o.w = f2bf(v.w);
  ((ushort4*)wb)[g] = o;
}

// ---------- K1: fused norm + transpose, x read from HBM ONCE via LDS stash ----------
__global__ __launch_bounds__(256) void k_xnt(const float* __restrict__ x,
                                             u16* __restrict__ xnt,
                                             float* __restrict__ nrm) {
  __shared__ float xs[256][65];
  __shared__ float part[4][64];
  __shared__ float invs[64];
  int b = blockIdx.x >> 6;
  int i0 = (blockIdx.x & 63) << 6;
  int il = threadIdx.x & 63;
  int q  = threadIdx.x >> 6;
  const float* xb = x + ((size_t)b << 20);
  float s = 0.f;
  #pragma unroll 8
  for (int k = 0; k < 64; ++k) {
    int c = q * 64 + k;
    float v = xb[((size_t)c << 12) + i0 + il];
    xs[c][il] = v;
    s += v * v;
  }
  part[q][il] = s;
  __syncthreads();
  if (q == 0) {
    float tot = part[0][il] + part[1][il] + part[2][il] + part[3][il];
    float n = fmaxf(sqrtf(tot), 1e-12f);
    nrm[(b << 12) + i0 + il] = n;
    invs[il] = 1.0f / n;
  }
  __syncthreads();
  float iv = invs[il];
  u16* dst = xnt + (((size_t)((b << 12) + i0 + il)) << 8) + q * 64;
  #pragma unroll
  for (int h = 0; h < 8; ++h) {
    u32 wv[4];
    #pragma unroll
    for (int e = 0; e < 4; ++e) {
      float lo = xs[q * 64 + h * 8 + 2 * e][il] * iv;
      float hi = xs[q * 64 + h * 8 + 2 * e + 1][il] * iv;
      wv[e] = (u32)f2bf(lo) | ((u32)f2bf(hi) << 16);
    }
    uint4 p; p.x = wv[0]; p.y = wv[1]; p.z = wv[2]; p.w = wv[3];
    *(uint4*)(dst + h * 8) = p;
  }
}

// ---------- K2: t[b][o][i] = bf16( nrm[i] * sum_c Wb[o][c]*xnt[i][c] + bias[o] ) ----------
__global__ __launch_bounds__(256) void k_tgemm(const u16* __restrict__ wb,
                                               const u16* __restrict__ xnt,
                                               const float* __restrict__ bias,
                                               const float* __restrict__ nrm,
                                               u16* __restrict__ t) {
  int b = blockIdx.x >> 6;
  int i0 = (blockIdx.x & 63) << 6;
  int w = threadIdx.x >> 6, l = threadIdx.x & 63;
  int lr = l & 15, lq = l >> 4;
  const u16* xb = xnt + (((size_t)((b << 12) + i0)) << 8);
  const f32x4 fz = {0.f, 0.f, 0.f, 0.f};
  f32x4 acc[4][4];
  #pragma unroll
  for (int a = 0; a < 4; ++a)
    #pragma unroll
    for (int c = 0; c < 4; ++c) acc[a][c] = fz;
  #pragma unroll 2
  for (int ks = 0; ks < 8; ++ks) {
    bf16x8 af[4], bfm[4];
    #pragma unroll
    for (int mf = 0; mf < 4; ++mf)
      af[mf] = *(const bf16x8*)(wb + ((64 * w + mf * 16 + lr) << 8) + ks * 32 + lq * 8);
    #pragma unroll
    for (int nf = 0; nf < 4; ++nf)
      bfm[nf] = *(const bf16x8*)(xb + ((nf * 16 + lr) << 8) + ks * 32 + lq * 8);
    #pragma unroll
    for (int mf = 0; mf < 4; ++mf)
      #pragma unroll
      for (int nf = 0; nf < 4; ++nf)
        acc[mf][nf] = __builtin_amdgcn_mfma_f32_16x16x32_bf16(af[mf], bfm[nf], acc[mf][nf], 0, 0, 0);
  }
  float nv[4];
  #pragma unroll
  for (int nf = 0; nf < 4; ++nf) nv[nf] = nrm[(b << 12) + i0 + nf * 16 + lr];
  #pragma unroll
  for (int mf = 0; mf < 4; ++mf) {
    int o = 64 * w + mf * 16 + lq * 4;
    #pragma unroll
    for (int r = 0; r < 4; ++r) {
      float bs = bias[o + r];
      u16* dst = t + (((size_t)((b << 8) + o + r)) << 12) + i0;
      #pragma unroll
      for (int nf = 0; nf < 4; ++nf) {
        float tv = acc[mf][nf][r] * nv[nf] + bs;
        dst[nf * 16 + lr] = f2bf(tv);
      }
    }
  }
}

// ---------- K3: fused  out[:, jblk(64)] = sum_i t[:, i(64)] * square(S^T) ----------
// 512 thr / 8 waves = (ih: i-half) x (jw: j-strip of 16). Lane-local P:
// wave computes S for its own (32i x 16j) patch; the stage-B B-fragment is
// built IN-WAVE via 8 ds_bpermute + 4 selects (no PT in LDS, no cross-wave
// dependency). ONE barrier/tile (Xi dbuf handoff, vmcnt-only). ih halves
// hold partial sums over i; combined once in an LDS epilogue.
// Xi LDS layout (conflict-free contiguous-1KB): slot s=ks*4+sub, unit
// lq*16+lr holds (row=sub*16+lr, chans ks*32+lq*8); staged via per-lane
// pre-permuted gl_lds source (m173).
__global__ __launch_bounds__(512, 1) void k_main(const u16* __restrict__ xnt,
                                                 const u16* __restrict__ tt,
                                                 float* __restrict__ out) {
  __shared__ __align__(16) char lds[65536];  // Xi0 32K | Xi1 32K (epilogue reuses)
  char* XiB[2]; XiB[0] = lds; XiB[1] = lds + 32768;

  int bid = blockIdx.x;
  int b = bid & 7;                           // batch -> XCD round-robin
  int jt = bid >> 3;
  int j0 = jt << 6;                          // JB = 64
  int tid = threadIdx.x;
  int w = tid >> 6, l = tid & 63;
  int lr = l & 15, lq = l >> 4;
  int ih = w >> 2;                           // i-half 0/1
  int jw = w & 3;                            // j-strip of 16

  const u16* xb = xnt + ((size_t)b << 20);   // [i][c] row 256 u16
  const u16* tb = tt  + ((size_t)b << 20);   // [c][i] row 4096 u16

  // loop-invariant Xj B-fragments for the wave's 16-j strip: 32 VGPR
  bf16x8 xj[8];
  {
    const u16* p = xb + ((size_t)(j0 + jw * 16 + lr) << 8) + lq * 8;
    #pragma unroll
    for (int ks = 0; ks < 8; ++ks)
      xj[ks] = *(const bf16x8*)(p + ks * 32);
  }

  const f32x4 fz = {0.f, 0.f, 0.f, 0.f};
  f32x4 acc[16];
  #pragma unroll
  for (int a = 0; a < 16; ++a) acc[a] = fz;

  // Xi staging: wave w stages slots s = w*4+q2 (ks=w>>... s>>2, sub=q2)
  u32 soff[4];
  #pragma unroll
  for (int q2 = 0; q2 < 4; ++q2)
    soff[q2] = (u32)(((q2 & 3) * 16 + lr) * 256 + ((w * 4 + q2) >> 2) * 32 + lq * 8);

  auto stageXi = [&](char* dstbase, int tile) {
    int i0s = (tile & 63) << 6;
    const u16* srcb = xb + ((size_t)i0s << 8);
    #pragma unroll
    for (int q2 = 0; q2 < 4; ++q2)
      gld16(srcb + soff[q2], dstbase + (w * 4 + q2) * 1024);
  };

  stageXi(XiB[0], 0);
  asm volatile("s_waitcnt vmcnt(0)" ::: "memory");
  __builtin_amdgcn_s_barrier();

  // bpermute source-lane addresses (bytes): src = 32*(lq&1) + 16*(m>>1) + lr
  int bp0 = (((l >> 4) & 1) * 32 + (l & 15)) * 4;  // m = 0,1
  int bp1 = bp0 + 64;                              // m = 2,3
  int selhi = (l >> 5);                            // lq>>1: which i-frag

  for (int it = 0; it < 64; ++it) {
    const int cur = it & 1;
    const int i0 = it << 6;
    char* xiC = XiB[cur];

    // pin xj: loop-carried -> no rematerialization
    #pragma unroll
    for (int ks = 0; ks < 8; ++ks) asm volatile("" : "+v"(xj[ks]));

    // t A-frags, first half (mf 0..7), i-window = i0 + 32*ih
    bf16x8 tfrA[8];
    #pragma unroll
    for (int mf = 0; mf < 8; ++mf)
      tfrA[mf] = *(const bf16x8*)(tb + ((size_t)(mf * 16 + lr) << 12) + i0 + 32 * ih + lq * 8);

    stageXi(XiB[cur ^ 1], it + 1);           // prefetch next Xi (4 gl_lds)

    // ---- stage A: S patch [32i x 16j], K=256, contiguous-1KB LDS reads ----
    f32x4 s0 = fz, s1 = fz;
    const char* ab = xiC + (2 * ih) * 1024 + l * 16;
    __builtin_amdgcn_s_setprio(1);
    {
      bf16x8 bfr[8];
      #pragma unroll
      for (int ks = 0; ks < 8; ++ks) bfr[ks] = *(const bf16x8*)(ab + ks * 4096);
      #pragma unroll
      for (int ks = 0; ks < 8; ++ks)
        s0 = __builtin_amdgcn_mfma_f32_16x16x32_bf16(bfr[ks], xj[ks], s0, 0, 0, 0);
    }
    {
      bf16x8 bfr[8];
      #pragma unroll
      for (int ks = 0; ks < 8; ++ks) bfr[ks] = *(const bf16x8*)(ab + 1024 + ks * 4096);
      #pragma unroll
      for (int ks = 0; ks < 8; ++ks)
        s1 = __builtin_amdgcn_mfma_f32_16x16x32_bf16(bfr[ks], xj[ks], s1, 0, 0, 0);
    }
    __builtin_amdgcn_s_setprio(0);

    // t A-frags, second half (mf 8..15)
    bf16x8 tfrB[8];
    #pragma unroll
    for (int mf = 0; mf < 8; ++mf)
      tfrB[mf] = *(const bf16x8*)(tb + ((size_t)((mf + 8) * 16 + lr) << 12) + i0 + 32 * ih + lq * 8);

    // square + pack: pk[pair][if_]  (pair: r01 / r23)
    u32 pk[2][2];
    pk[0][0] = (u32)f2bf(s0[0] * s0[0]) | ((u32)f2bf(s0[1] * s0[1]) << 16);
    pk[1][0] = (u32)f2bf(s0[2] * s0[2]) | ((u32)f2bf(s0[3] * s0[3]) << 16);
    pk[0][1] = (u32)f2bf(s1[0] * s1[0]) | ((u32)f2bf(s1[1] * s1[1]) << 16);
    pk[1][1] = (u32)f2bf(s1[2] * s1[2]) | ((u32)f2bf(s1[3] * s1[3]) << 16);

    // in-wave exchange -> stage-B B-fragment (P[i=8*lq+2m+{0,1}][j=lr])
    int bm[4];
    #pragma unroll
    for (int m = 0; m < 4; ++m) {
      int addr = (m < 2) ? bp0 : bp1;
      int X = __builtin_amdgcn_ds_bpermute(addr, (int)pk[m & 1][0]);
      int Y = __builtin_amdgcn_ds_bpermute(addr, (int)pk[m & 1][1]);
      bm[m] = selhi ? Y : X;
    }
    union { int4 i; bf16x8 v; } pu;
    pu.i.x = bm[0]; pu.i.y = bm[1]; pu.i.z = bm[2]; pu.i.w = bm[3];
    bf16x8 pfr = pu.v;

    // ---- stage B: acc[256c x 16j] += t[:, ih-window] . P ----
    __builtin_amdgcn_s_setprio(1);
    #pragma unroll
    for (int mf = 0; mf < 8; ++mf)
      acc[mf] = __builtin_amdgcn_mfma_f32_16x16x32_bf16(tfrA[mf], pfr, acc[mf], 0, 0, 0);
    #pragma unroll
    for (int mf = 0; mf < 8; ++mf)
      acc[mf + 8] = __builtin_amdgcn_mfma_f32_16x16x32_bf16(tfrB[mf], pfr, acc[mf + 8], 0, 0, 0);
    __builtin_amdgcn_s_setprio(0);

    asm volatile("s_waitcnt vmcnt(0)" ::: "memory");  // gl_lds(it+1) landed
    __builtin_amdgcn_sched_barrier(0);
    __builtin_amdgcn_s_barrier();                     // ONE barrier per tile
    __builtin_amdgcn_sched_barrier(0);
  }

  // ---- epilogue: combine ih partial sums via LDS, store fp32 ----
  if (ih == 1) {
    #pragma unroll
    for (int mf = 0; mf < 16; ++mf)
      *(f32x4*)(lds + jw * 16384 + mf * 1024 + l * 16) = acc[mf];
  }
  asm volatile("s_waitcnt lgkmcnt(0)" ::: "memory");
  __builtin_amdgcn_s_barrier();
  if (ih == 0) {
    #pragma unroll
    for (int mf = 0; mf < 16; ++mf) {
      f32x4 part = *(const f32x4*)(lds + jw * 16384 + mf * 1024 + l * 16);
      int c = (b << 8) + mf * 16 + lq * 4;
      int j = j0 + jw * 16 + lr;
      float* dst = out + ((size_t)c << 12) + j;
      #pragma unroll
      for (int r = 0; r < 4; ++r)
        dst[(size_t)r << 12] = acc[mf][r] + part[r];
    }
  }
}

extern "C" void kernel_launch(void* const* d_in, const int* in_sizes, int n_in,
                              void* d_out, int out_size, void* d_ws, size_t ws_size,
                              hipStream_t stream) {
  const float* x    = (const float*)d_in[0];
  const float* W    = (const float*)d_in[1];
  const float* bias = (const float*)d_in[2];
  float* out = (float*)d_out;

  char* ws = (char*)d_ws;
  u16*   xnt = (u16*)(ws);                                  // 16 MiB  [b][i][c] bf16
  u16*   tt  = (u16*)(ws + ((size_t)16 << 20));             // 16 MiB  [b][c][i] bf16
  u16*   wb  = (u16*)(ws + ((size_t)32 << 20));             // 128 KiB
  float* nrm = (float*)(ws + ((size_t)33 << 20));           // 128 KiB

  hipLaunchKernelGGL(k_wb,    dim3(64),  dim3(256), 0, stream, W, wb);
  hipLaunchKernelGGL(k_xnt,   dim3(512), dim3(256), 0, stream, x, xnt, nrm);
  hipLaunchKernelGGL(k_tgemm, dim3(512), dim3(256), 0, stream, wb, xnt, bias, nrm, tt);
  hipLaunchKernelGGL(k_main,  dim3(512), dim3(512), 0, stream, xnt, tt, out);
}